// Round 1
// baseline (151.479 us; speedup 1.0000x reference)
//
#include <hip/hip_runtime.h>
#include <math.h>

#define NB 64
#define NT 2048
#define NH 512
#define NOUT 128
#define TCH 32          // t-chunks for context pass
#define TPC (NT / TCH)  // 64 timesteps per chunk

// ---------------------------------------------------------------------------
// K1: v[b,h] = sum_k W_score[h,k] * h_t[b,k]   (h_t = hidden[b, T-1, :])
// ---------------------------------------------------------------------------
__global__ __launch_bounds__(256) void k_v(const float* __restrict__ hidden,
                                           const float* __restrict__ Wscore,
                                           float* __restrict__ v) {
    __shared__ float ht[NH];
    const int b = blockIdx.x;
    const float* hrow = hidden + ((size_t)b * NT + (NT - 1)) * NH;
    for (int k = threadIdx.x; k < NH; k += 256) ht[k] = hrow[k];
    __syncthreads();
    for (int h = threadIdx.x; h < NH; h += 256) {
        const float4* wr = reinterpret_cast<const float4*>(Wscore + (size_t)h * NH);
        float acc = 0.f;
#pragma unroll 8
        for (int k4 = 0; k4 < NH / 4; ++k4) {
            float4 w = wr[k4];
            acc += w.x * ht[k4 * 4 + 0] + w.y * ht[k4 * 4 + 1] +
                   w.z * ht[k4 * 4 + 2] + w.w * ht[k4 * 4 + 3];
        }
        v[b * NH + h] = acc;
    }
}

// ---------------------------------------------------------------------------
// K2: score[b,t] = hidden[b,t,:] . v[b,:]   — one wave per (b,t) row
// ---------------------------------------------------------------------------
__global__ __launch_bounds__(256) void k_score(const float* __restrict__ hidden,
                                               const float* __restrict__ v,
                                               float* __restrict__ score) {
    const int wid = threadIdx.x >> 6;
    const int lane = threadIdx.x & 63;
    const long r = (long)blockIdx.x * 4 + wid;  // row in [0, B*T)
    const int b = (int)(r / NT);
    const float4* hrow = reinterpret_cast<const float4*>(hidden + r * NH);
    const float4* vrow = reinterpret_cast<const float4*>(v + (size_t)b * NH);
    float acc = 0.f;
#pragma unroll
    for (int i = 0; i < 2; ++i) {
        int idx = i * 64 + lane;  // float4 index in [0,128)
        float4 h4 = hrow[idx];
        float4 v4 = vrow[idx];
        acc += h4.x * v4.x + h4.y * v4.y + h4.z * v4.z + h4.w * v4.w;
    }
#pragma unroll
    for (int off = 32; off >= 1; off >>= 1) acc += __shfl_xor(acc, off, 64);
    if (lane == 0) score[r] = acc;
}

// ---------------------------------------------------------------------------
// K3: weights[b,:] = softmax(score[b,:])  — one block per batch
// ---------------------------------------------------------------------------
__global__ __launch_bounds__(256) void k_softmax(const float* __restrict__ score,
                                                 float* __restrict__ w) {
    const int b = blockIdx.x;
    const float* s = score + (size_t)b * NT;
    const int wid = threadIdx.x >> 6, lane = threadIdx.x & 63;
    float loc[8];
    float m = -INFINITY;
#pragma unroll
    for (int j = 0; j < 8; ++j) {
        loc[j] = s[threadIdx.x + j * 256];
        m = fmaxf(m, loc[j]);
    }
#pragma unroll
    for (int off = 32; off >= 1; off >>= 1) m = fmaxf(m, __shfl_xor(m, off, 64));
    __shared__ float redm[4];
    if (lane == 0) redm[wid] = m;
    __syncthreads();
    m = fmaxf(fmaxf(redm[0], redm[1]), fmaxf(redm[2], redm[3]));

    float sum = 0.f;
#pragma unroll
    for (int j = 0; j < 8; ++j) {
        loc[j] = __expf(loc[j] - m);
        sum += loc[j];
    }
#pragma unroll
    for (int off = 32; off >= 1; off >>= 1) sum += __shfl_xor(sum, off, 64);
    __shared__ float reds[4];
    if (lane == 0) reds[wid] = sum;
    __syncthreads();
    sum = reds[0] + reds[1] + reds[2] + reds[3];
    const float inv = 1.f / sum;
#pragma unroll
    for (int j = 0; j < 8; ++j)
        w[(size_t)b * NT + threadIdx.x + j * 256] = loc[j] * inv;
}

// ---------------------------------------------------------------------------
// K4: partial context: partial[b,tc,h] = sum_{t in chunk tc} w[b,t]*hidden[b,t,h]
//     grid = B*TCH blocks; thread owns one float2 column (h pair)
// ---------------------------------------------------------------------------
__global__ __launch_bounds__(256) void k_ctx(const float* __restrict__ hidden,
                                             const float* __restrict__ w,
                                             float* __restrict__ partial) {
    const int b = blockIdx.x / TCH;
    const int tc = blockIdx.x % TCH;
    const int t0 = tc * TPC;
    const float2* hp =
        reinterpret_cast<const float2*>(hidden + ((size_t)b * NT + t0) * NH);
    const float* wp = w + (size_t)b * NT + t0;
    const int c = threadIdx.x;  // float2 column in [0,256)
    float2 acc = {0.f, 0.f};
#pragma unroll 4
    for (int tt = 0; tt < TPC; ++tt) {
        float wt = wp[tt];
        float2 h2 = hp[(size_t)tt * 256 + c];
        acc.x += wt * h2.x;
        acc.y += wt * h2.y;
    }
    reinterpret_cast<float2*>(partial + ((size_t)b * TCH + tc) * NH)[c] = acc;
}

// ---------------------------------------------------------------------------
// K5: reduce partials -> context, concat h_t, GEMV with W_out, tanh
//     one block (128 threads) per batch
// ---------------------------------------------------------------------------
__global__ __launch_bounds__(128) void k_out(const float* __restrict__ hidden,
                                             const float* __restrict__ partial,
                                             const float* __restrict__ Wout,
                                             float* __restrict__ out) {
    __shared__ float pre[2 * NH];
    const int b = blockIdx.x;
#pragma unroll
    for (int j = 0; j < 4; ++j) {
        int h = threadIdx.x + j * 128;
        float acc = 0.f;
#pragma unroll
        for (int tc = 0; tc < TCH; ++tc)
            acc += partial[((size_t)b * TCH + tc) * NH + h];
        pre[h] = acc;
    }
    const float* hrow = hidden + ((size_t)b * NT + (NT - 1)) * NH;
#pragma unroll
    for (int j = 0; j < 4; ++j) {
        int h = threadIdx.x + j * 128;
        pre[NH + h] = hrow[h];
    }
    __syncthreads();
    const int o = threadIdx.x;
    float acc = 0.f;
    for (int j = 0; j < 2 * NH; ++j) acc += pre[j] * Wout[(size_t)j * NOUT + o];
    out[(size_t)b * NOUT + o] = tanhf(acc);
}

// ---------------------------------------------------------------------------
extern "C" void kernel_launch(void* const* d_in, const int* in_sizes, int n_in,
                              void* d_out, int out_size, void* d_ws, size_t ws_size,
                              hipStream_t stream) {
    const float* hidden = (const float*)d_in[0];  // (B,T,H)
    const float* Wscore = (const float*)d_in[1];  // (H,H)
    const float* Wout = (const float*)d_in[2];    // (2H,OUT)
    float* out = (float*)d_out;                   // (B,OUT) fp32

    float* ws = (float*)d_ws;
    float* v = ws;                         // B*H
    float* score = v + NB * NH;            // B*T
    float* wgt = score + NB * NT;          // B*T
    float* partial = wgt + NB * NT;        // B*TCH*H

    k_v<<<NB, 256, 0, stream>>>(hidden, Wscore, v);
    k_score<<<NB * NT / 4, 256, 0, stream>>>(hidden, v, score);
    k_softmax<<<NB, 256, 0, stream>>>(score, wgt);
    k_ctx<<<NB * TCH, 256, 0, stream>>>(hidden, wgt, partial);
    k_out<<<NB, 128, 0, stream>>>(hidden, partial, Wout, out);
}

// Round 2
// 96.391 us; speedup vs baseline: 1.5715x; 1.5715x over previous
//
#include <hip/hip_runtime.h>
#include <math.h>

#define NB 64
#define NT 2048
#define NH 512
#define NOUT 128
#define TCH 32          // t-chunks (blocks per batch) for flash pass
#define TPC 64          // timesteps per chunk (NT/TCH)
#define RPW 16          // rows per wave (TPC / 4 waves)

// ---------------------------------------------------------------------------
// K1: v[b,h] = sum_k W_score[h,k] * h_t[b,k]   (h_t = hidden[b, T-1, :])
// grid (NB, 4): block computes 128 h-values for one batch.
// ---------------------------------------------------------------------------
__global__ __launch_bounds__(128) void k_v(const float* __restrict__ hidden,
                                           const float* __restrict__ Wscore,
                                           float* __restrict__ v) {
    __shared__ float ht[NH];
    const int b = blockIdx.x;
    const float* hrow = hidden + ((size_t)b * NT + (NT - 1)) * NH;
    for (int k = threadIdx.x; k < NH; k += 128) ht[k] = hrow[k];
    __syncthreads();
    const int h = blockIdx.y * 128 + threadIdx.x;
    const float4* wr = reinterpret_cast<const float4*>(Wscore + (size_t)h * NH);
    float acc = 0.f;
#pragma unroll 8
    for (int k4 = 0; k4 < NH / 4; ++k4) {
        float4 w = wr[k4];
        acc += w.x * ht[k4 * 4 + 0] + w.y * ht[k4 * 4 + 1] +
               w.z * ht[k4 * 4 + 2] + w.w * ht[k4 * 4 + 3];
    }
    v[(size_t)b * NH + h] = acc;
}

// ---------------------------------------------------------------------------
// K2 (flash): one pass over hidden. Per (b, chunk): each wave owns 16 rows;
// per row, read the 512-float row ONCE, use it for the score dot AND the
// online-softmax-weighted context accumulation. Cross-wave combine in LDS.
// Outputs per chunk: pctx[b,tc,0:H] (unnormalized, at max m_b), pm, pl.
// ---------------------------------------------------------------------------
__global__ __launch_bounds__(256) void k_flash(const float* __restrict__ hidden,
                                               const float* __restrict__ v,
                                               float* __restrict__ pctx,
                                               float* __restrict__ pm,
                                               float* __restrict__ pl) {
    const int b = blockIdx.x / TCH;
    const int tc = blockIdx.x % TCH;
    const int wid = threadIdx.x >> 6;
    const int lane = threadIdx.x & 63;

    const float4* vb = reinterpret_cast<const float4*>(v + (size_t)b * NH);
    const float4 v0 = vb[lane];
    const float4 v1 = vb[64 + lane];

    const float4* hbase = reinterpret_cast<const float4*>(
        hidden + ((size_t)b * NT + tc * TPC + wid * RPW) * NH);

    float4 c0 = {0.f, 0.f, 0.f, 0.f}, c1 = {0.f, 0.f, 0.f, 0.f};
    float m = -INFINITY, l = 0.f;

#pragma unroll 4
    for (int r = 0; r < RPW; ++r) {
        float4 h0 = hbase[(size_t)r * 128 + lane];
        float4 h1 = hbase[(size_t)r * 128 + 64 + lane];
        float s = h0.x * v0.x + h0.y * v0.y + h0.z * v0.z + h0.w * v0.w +
                  h1.x * v1.x + h1.y * v1.y + h1.z * v1.z + h1.w * v1.w;
#pragma unroll
        for (int off = 32; off >= 1; off >>= 1) s += __shfl_xor(s, off, 64);
        // wave-uniform online softmax update
        if (s > m) {
            float sc = __expf(m - s);
            c0.x *= sc; c0.y *= sc; c0.z *= sc; c0.w *= sc;
            c1.x *= sc; c1.y *= sc; c1.z *= sc; c1.w *= sc;
            l *= sc;
            m = s;
        }
        float p = __expf(s - m);
        l += p;
        c0.x += p * h0.x; c0.y += p * h0.y; c0.z += p * h0.z; c0.w += p * h0.w;
        c1.x += p * h1.x; c1.y += p * h1.y; c1.z += p * h1.z; c1.w += p * h1.w;
    }

    // cross-wave combine
    __shared__ float cl[4][NH];
    __shared__ float ml[4], ll[4];
    reinterpret_cast<float4*>(cl[wid])[lane] = c0;
    reinterpret_cast<float4*>(cl[wid])[64 + lane] = c1;
    if (lane == 0) { ml[wid] = m; ll[wid] = l; }
    __syncthreads();

    const float mb = fmaxf(fmaxf(ml[0], ml[1]), fmaxf(ml[2], ml[3]));
    const float e0 = __expf(ml[0] - mb), e1 = __expf(ml[1] - mb);
    const float e2 = __expf(ml[2] - mb), e3 = __expf(ml[3] - mb);

    const int h2 = threadIdx.x;  // float2 column, 0..255
    float2 a;
    a.x = cl[0][2 * h2] * e0 + cl[1][2 * h2] * e1 +
          cl[2][2 * h2] * e2 + cl[3][2 * h2] * e3;
    a.y = cl[0][2 * h2 + 1] * e0 + cl[1][2 * h2 + 1] * e1 +
          cl[2][2 * h2 + 1] * e2 + cl[3][2 * h2 + 1] * e3;
    reinterpret_cast<float2*>(pctx + ((size_t)b * TCH + tc) * NH)[h2] = a;
    if (threadIdx.x == 0) {
        pm[b * TCH + tc] = mb;
        pl[b * TCH + tc] = ll[0] * e0 + ll[1] * e1 + ll[2] * e2 + ll[3] * e3;
    }
}

// ---------------------------------------------------------------------------
// K3: combine chunk partials -> context, concat h_t, GEMV W_out, tanh.
// One block (256 threads) per batch.
// ---------------------------------------------------------------------------
__global__ __launch_bounds__(256) void k_out(const float* __restrict__ hidden,
                                             const float* __restrict__ pctx,
                                             const float* __restrict__ pm,
                                             const float* __restrict__ pl,
                                             const float* __restrict__ Wout,
                                             float* __restrict__ out) {
    __shared__ float pre[2 * NH];
    __shared__ float red[256];
    const int b = blockIdx.x;

    // global max / denom across chunks (redundant per thread; tiny, cached)
    float Mb = -INFINITY;
#pragma unroll
    for (int tc = 0; tc < TCH; ++tc) Mb = fmaxf(Mb, pm[b * TCH + tc]);
    float Lb = 0.f;
#pragma unroll
    for (int tc = 0; tc < TCH; ++tc) Lb += pl[b * TCH + tc] * __expf(pm[b * TCH + tc] - Mb);
    const float invL = 1.f / Lb;

    // combine context; thread owns one float2 column
    const int h2 = threadIdx.x;
    float2 a = {0.f, 0.f};
    for (int tc = 0; tc < TCH; ++tc) {
        float e = __expf(pm[b * TCH + tc] - Mb);
        float2 p = reinterpret_cast<const float2*>(pctx + ((size_t)b * TCH + tc) * NH)[h2];
        a.x += e * p.x;
        a.y += e * p.y;
    }
    pre[2 * h2] = a.x * invL;
    pre[2 * h2 + 1] = a.y * invL;

    const float* hrow = hidden + ((size_t)b * NT + (NT - 1)) * NH;
    float2 hh = reinterpret_cast<const float2*>(hrow)[h2];
    pre[NH + 2 * h2] = hh.x;
    pre[NH + 2 * h2 + 1] = hh.y;
    __syncthreads();

    // GEMV: 128 outputs, 2 threads per output (split j-range)
    const int o = threadIdx.x & 127;
    const int half = threadIdx.x >> 7;
    float acc = 0.f;
    const int j0 = half * NH;
#pragma unroll 4
    for (int j = j0; j < j0 + NH; ++j) acc += pre[j] * Wout[(size_t)j * NOUT + o];
    red[threadIdx.x] = acc;
    __syncthreads();
    if (half == 0) out[(size_t)b * NOUT + o] = tanhf(red[o] + red[128 + o]);
}

// ---------------------------------------------------------------------------
extern "C" void kernel_launch(void* const* d_in, const int* in_sizes, int n_in,
                              void* d_out, int out_size, void* d_ws, size_t ws_size,
                              hipStream_t stream) {
    const float* hidden = (const float*)d_in[0];  // (B,T,H)
    const float* Wscore = (const float*)d_in[1];  // (H,H)
    const float* Wout = (const float*)d_in[2];    // (2H,OUT)
    float* out = (float*)d_out;                   // (B,OUT) fp32

    float* ws = (float*)d_ws;
    float* v = ws;                          // NB*NH
    float* pctx = v + NB * NH;              // NB*TCH*NH
    float* pm = pctx + (size_t)NB * TCH * NH;  // NB*TCH
    float* pl = pm + NB * TCH;              // NB*TCH

    k_v<<<dim3(NB, 4), 128, 0, stream>>>(hidden, Wscore, v);
    k_flash<<<NB * TCH, 256, 0, stream>>>(hidden, v, pctx, pm, pl);
    k_out<<<NB, 256, 0, stream>>>(hidden, pctx, pm, pl, Wout, out);
}